// Round 7
// baseline (349.776 us; speedup 1.0000x reference)
//
#include <hip/hip_runtime.h>
#include <hip/hip_bf16.h>
#include <math.h>

// IntentionHeads: per-token 2-head MLP with head selection. (f32 in, f32 out)
//   X [65536,512] f32; layer1 H=GELU(X@W1^T+b1) (W1 [256,512] per head);
//   layer2 logits=H@W2^T+b2 (W2 [6,256]/[2,256]);
//   out f32: logits[65536,6] ++ v_mask[65536] ++ p_mask[65536]
//
// R6 (139.7us) was VALU-bound (54%): software RNE cvt ~11 ops/val and W1
// re-converted per 64-token block (1024x redundant per head). This round:
//  - BOTH heads fused per block: 512 thr / 8 waves, 64 tokens x 512 combined
//    hidden (cols 0-255 vehicle, 256-511 ped). X staged once; W1-cvt halved;
//    output ownership now intra-block.
//  - Fast packed RNE: u += 0x7FFF + ((u>>16)&1) then v_perm_b32 byte-pack
//    (5 VALU per pair vs ~22).
//  - LDS: staging At[64][40]+Bt[512][40] bf16 (46KB) unioned with H[64][520]
//    (65KB) -> 2 blocks/CU; frag-read row strides land 2-way on banks (free).

#define TOKENS 65536
#define DIM    512
#define HID    256
#define ASTR   40    // staged tile row stride in bf16 (32 + 8 pad, 16B mult)
#define HSTR   520   // combined H row stride in bf16 (512 + 8 pad, 16B mult)

using short8 = __attribute__((ext_vector_type(8))) short;  // 8 x bf16
using f32x4  = __attribute__((ext_vector_type(4))) float;

// packed RNE f32->bf16 pair: 2x(v_bfe+v_add3) + v_perm_b32
__device__ __forceinline__ unsigned int pkrne(float a, float b) {
    unsigned int ua = __float_as_uint(a);
    unsigned int ub = __float_as_uint(b);
    ua += 0x7FFFu + ((ua >> 16) & 1u);
    ub += 0x7FFFu + ((ub >> 16) & 1u);
    // result bytes: [ua.b2, ua.b3, ub.b2, ub.b3]  (sel 0-3 from src1=ua)
    return __builtin_amdgcn_perm(ub, ua, 0x07060302u);
}

__device__ __forceinline__ uint2 cvt4(f32x4 v) {
    return make_uint2(pkrne(v[0], v[1]), pkrne(v[2], v[3]));
}

// 8 consecutive f32 -> bf16x8 fragment (layer-2 W2 loads)
__device__ __forceinline__ short8 cvt8(const float* __restrict__ p) {
    f32x4 a = *(const f32x4*)p;
    f32x4 b = *(const f32x4*)(p + 4);
    union { uint2 u[2]; short8 s; } r;
    r.u[0] = cvt4(a);
    r.u[1] = cvt4(b);
    return r.s;
}

__device__ __forceinline__ __hip_bfloat16 bf16rne(float x) {
    unsigned int u = __float_as_uint(x);
    u += 0x7FFFu + ((u >> 16) & 1u);
    unsigned short hs = (unsigned short)(u >> 16);
    return *(__hip_bfloat16*)&hs;
}

__device__ __forceinline__ float gelu_exact(float x) {
    // exact (erf) GELU, matches jax.nn.gelu(approximate=False)
    return 0.5f * x * (1.0f + erff(x * 0.7071067811865475f));
}

__global__ __launch_bounds__(512, 4)
void intention_heads_kernel(const float* __restrict__ X,
                            const int* __restrict__ ids,
                            const float* __restrict__ vW1,
                            const float* __restrict__ vb1,
                            const float* __restrict__ vW2,
                            const float* __restrict__ vb2,
                            const float* __restrict__ pW1,
                            const float* __restrict__ pb1,
                            const float* __restrict__ pW2,
                            const float* __restrict__ pb2,
                            float* __restrict__ out)
{
    // LDS union: staging At[64][ASTR] (5.1KB) + Bt[512][ASTR] (41KB) = 46KB,
    // then H[64][HSTR] = 65KB. 66560 B -> 2 blocks/CU.
    __shared__ __align__(16) unsigned char smem[64 * HSTR * 2];
    __hip_bfloat16* At = (__hip_bfloat16*)smem;                    // [64][ASTR]
    __hip_bfloat16* Bt = (__hip_bfloat16*)(smem + 64 * ASTR * 2);  // [512][ASTR]
    __hip_bfloat16* H  = (__hip_bfloat16*)smem;                    // [64][HSTR]

    const int row0 = blockIdx.x * 64;    // 64 tokens per block, both heads

    const int tid  = threadIdx.x;        // 0..511
    const int wave = tid >> 6;           // 0..7 -> combined hidden cols w*64
    const int lane = tid & 63;
    const int quad = lane >> 4;
    const int l16  = lane & 15;
    const int wcol = wave * 64;          // 0..448 (0-255 veh, 256-511 ped)

    // staging decomposition: thread owns f32x4 at col q*4 of rows:
    //   A: r        B: r+64e (e=0..3 vehicle) / 256+r+64e (ped)
    const int q = tid & 7;
    const int r = tid >> 3;              // 0..63
    const float* Xs = X   + (long)(row0 + r) * DIM + q * 4;
    const float* Wv = vW1 + (long)r * DIM + q * 4;
    const float* Wp = pW1 + (long)r * DIM + q * 4;

    f32x4 acc[4][4];
    #pragma unroll
    for (int i = 0; i < 4; ++i)
        #pragma unroll
        for (int j = 0; j < 4; ++j)
            acc[i][j] = (f32x4){0.f, 0.f, 0.f, 0.f};

    // ---------------- layer 1: 64 tokens x 512 combined hidden, K=512 -----
    for (int k0 = 0; k0 < DIM; k0 += 32) {
        {
            f32x4 v = *(const f32x4*)(Xs + k0);
            *(uint2*)&At[r * ASTR + q * 4] = cvt4(v);
        }
        #pragma unroll
        for (int e = 0; e < 4; ++e) {
            f32x4 v = *(const f32x4*)(Wv + (long)e * 64 * DIM + k0);
            *(uint2*)&Bt[(r + 64 * e) * ASTR + q * 4] = cvt4(v);
        }
        #pragma unroll
        for (int e = 0; e < 4; ++e) {
            f32x4 v = *(const f32x4*)(Wp + (long)e * 64 * DIM + k0);
            *(uint2*)&Bt[(256 + r + 64 * e) * ASTR + q * 4] = cvt4(v);
        }
        __syncthreads();

        short8 af[4], bf_[4];
        #pragma unroll
        for (int i = 0; i < 4; ++i)
            af[i] = *(const short8*)&At[(i * 16 + l16) * ASTR + quad * 8];
        #pragma unroll
        for (int j = 0; j < 4; ++j)
            bf_[j] = *(const short8*)&Bt[(wcol + j * 16 + l16) * ASTR + quad * 8];

        #pragma unroll
        for (int i = 0; i < 4; ++i)
            #pragma unroll
            for (int j = 0; j < 4; ++j)
                acc[i][j] = __builtin_amdgcn_mfma_f32_16x16x32_bf16(af[i], bf_[j], acc[i][j], 0, 0, 0);
        __syncthreads();   // frag reads done before next iter's writes / H
    }

    // ------------- bias + GELU, stage combined H tile (bf16) --------------
    // C/D layout: col = l16, row = quad*4 + rr (within each 16x16 tile)
    const float* b1 = (wave < 4) ? vb1 : pb1;
    const int    bo = (wave < 4) ? wcol : (wcol - 256);
    float b1v[4];
    #pragma unroll
    for (int j = 0; j < 4; ++j)
        b1v[j] = b1[bo + j * 16 + l16];

    #pragma unroll
    for (int i = 0; i < 4; ++i) {
        #pragma unroll
        for (int j = 0; j < 4; ++j) {
            const int col = wcol + j * 16 + l16;
            #pragma unroll
            for (int rr = 0; rr < 4; ++rr) {
                const int row = i * 16 + quad * 4 + rr;
                H[row * HSTR + col] = bf16rne(gelu_exact(acc[i][j][rr] + b1v[j]));
            }
        }
    }
    __syncthreads();

    // ---------------- layer 2: per-wave 16 tokens x one head --------------
    // wave pair g = wave>>1 covers tokens [g*16, g*16+16); wave&1 picks head.
    const int g     = wave >> 1;
    const int isPed = wave & 1;
    const int tokb  = g * 16;
    const float* W2 = isPed ? pW2 : vW2;
    const float* b2 = isPed ? pb2 : vb2;
    const int  nOut = isPed ? 2 : 6;
    const int  hoff = isPed ? 256 : 0;

    f32x4 acc2 = (f32x4){0.f, 0.f, 0.f, 0.f};
    const short* hbase = (const short*)&H[(tokb + l16) * HSTR + hoff + quad * 8];
    #pragma unroll
    for (int k0 = 0; k0 < HID; k0 += 32) {
        short8 af = *(const short8*)(hbase + k0);
        short8 bfrag = (short8){0, 0, 0, 0, 0, 0, 0, 0};
        if (l16 < nOut)
            bfrag = cvt8(W2 + l16 * HID + k0 + quad * 8);
        acc2 = __builtin_amdgcn_mfma_f32_16x16x32_bf16(af, bfrag, acc2, 0, 0, 0);
    }

    // ---------------- masked epilogue (f32 writes) ------------------------
    const float b2v = (l16 < nOut) ? b2[l16] : 0.0f;

    #pragma unroll
    for (int rr = 0; rr < 4; ++rr) {
        const int t = row0 + tokb + quad * 4 + rr;
        const int type = ids[t];
        if (!isPed) {
            if (l16 == 0) {
                out[TOKENS * 6 + t] = (type == 1) ? 1.0f : 0.0f;
                out[TOKENS * 7 + t] = (type == 2) ? 1.0f : 0.0f;
            }
            if (l16 < 6) {
                if (type == 1)
                    out[t * 6 + l16] = acc2[rr] + b2v;
                else if (type != 2)
                    out[t * 6 + l16] = 0.0f;        // types 0,3 -> zeros
                // type==2 slots written by the pedestrian wave
            }
        } else {
            if (l16 < 6 && type == 2)
                out[t * 6 + l16] = (l16 < 2) ? (acc2[rr] + b2v) : 0.0f;
        }
    }
}

extern "C" void kernel_launch(void* const* d_in, const int* in_sizes, int n_in,
                              void* d_out, int out_size, void* d_ws, size_t ws_size,
                              hipStream_t stream) {
    (void)n_in; (void)out_size; (void)d_ws; (void)ws_size;
    const float* X   = (const float*)d_in[0];
    const int*   ids = (const int*)d_in[1];
    const float* vW1 = (const float*)d_in[2];
    const float* vb1 = (const float*)d_in[3];
    const float* vW2 = (const float*)d_in[4];
    const float* vb2 = (const float*)d_in[5];
    const float* pW1 = (const float*)d_in[6];
    const float* pb1 = (const float*)d_in[7];
    const float* pW2 = (const float*)d_in[8];
    const float* pb2 = (const float*)d_in[9];
    float* out = (float*)d_out;

    const int tokens = in_sizes[1];       // 65536
    const int grid   = tokens / 64;       // both heads fused per block

    hipLaunchKernelGGL(intention_heads_kernel, dim3(grid), dim3(512), 0, stream,
                       X, ids, vW1, vb1, vW2, vb2, pW1, pb1, pW2, pb2, out);
}

// Round 8
// 281.265 us; speedup vs baseline: 1.2436x; 1.2436x over previous
//
#include <hip/hip_runtime.h>
#include <hip/hip_bf16.h>
#include <math.h>

// IntentionHeads: per-token 2-head MLP with head selection. (f32 in, f32 out)
//   X [65536,512] f32; layer1 H=GELU(X@W1^T+b1) (W1 [256,512] per head);
//   layer2 logits=H@W2^T+b2 (W2 [6,256]/[2,256]);
//   out f32: logits[65536,6] ++ v_mask[65536] ++ p_mask[65536]
//
// R7 (205us) was latency-bound: no prefetch, B staged+converted per block.
// R8 plan:
//  - prep kernel converts W1(both) -> ws bf16 Wc[512][512] and W2 -> ws bf16
//    W2c[32][256] (16 zero-padded rows per head) once per launch (~5us).
//  - main kernel (256 thr, 64 tok x 256 hid, one head/block, grid 2048):
//    B-frags = direct global_load_dwordx4 from Wc (L2-hot, no LDS, no cvt),
//    prefetched one K-iter ahead into regs (latency hidden, no barrier dep).
//    X tile -> LDS bf16, double-buffered, ONE barrier per K-iter, register
//    prefetch of next X chunk. LDS = max(2x5KB staging, 33.8KB H) -> 4 blk/CU.

#define TOKENS 65536
#define DIM    512
#define HID    256
#define ASTR   40    // X staging row stride in bf16 (32 + 8 pad, 16B mult)
#define HSTR   264   // H row stride in bf16 (256 + 8 pad, 16B mult)

using short8 = __attribute__((ext_vector_type(8))) short;  // 8 x bf16
using f32x4  = __attribute__((ext_vector_type(4))) float;

// packed RNE f32->bf16 pair (v_perm byte-pack)
__device__ __forceinline__ unsigned int pkrne(float a, float b) {
    unsigned int ua = __float_as_uint(a);
    unsigned int ub = __float_as_uint(b);
    ua += 0x7FFFu + ((ua >> 16) & 1u);
    ub += 0x7FFFu + ((ub >> 16) & 1u);
    return __builtin_amdgcn_perm(ub, ua, 0x07060302u);  // [ua.hi16, ub.hi16]
}

__device__ __forceinline__ uint2 cvt4(f32x4 v) {
    return make_uint2(pkrne(v[0], v[1]), pkrne(v[2], v[3]));
}

__device__ __forceinline__ __hip_bfloat16 bf16rne(float x) {
    unsigned int u = __float_as_uint(x);
    u += 0x7FFFu + ((u >> 16) & 1u);
    unsigned short hs = (unsigned short)(u >> 16);
    return *(__hip_bfloat16*)&hs;
}

__device__ __forceinline__ float gelu_exact(float x) {
    // exact (erf) GELU, matches jax.nn.gelu(approximate=False)
    return 0.5f * x * (1.0f + erff(x * 0.7071067811865475f));
}

// ---------------- prep: weights f32 -> bf16 in workspace --------------------
// Wc  [512][512]: rows 0-255 vW1, 256-511 pW1
// W2c [32][256]:  rows 0-5 vW2, 6-15 zero, 16-17 pW2, 18-31 zero
__global__ __launch_bounds__(256)
void prep_kernel(const float* __restrict__ vW1, const float* __restrict__ pW1,
                 const float* __restrict__ vW2, const float* __restrict__ pW2,
                 __hip_bfloat16* __restrict__ Wc, __hip_bfloat16* __restrict__ W2c)
{
    const int i = blockIdx.x * 256 + threadIdx.x;   // f32x4 chunk index
    if (i < 65536) {                                // W1: 262144 elems
        const int flat = i * 4;
        f32x4 v = (flat < 131072) ? *(const f32x4*)(vW1 + flat)
                                  : *(const f32x4*)(pW1 + flat - 131072);
        *(uint2*)(Wc + flat) = cvt4(v);
    } else if (i < 65536 + 2048) {                  // W2c: 8192 elems
        const int flat = (i - 65536) * 4;
        const int row = flat >> 8, col = flat & 255;
        f32x4 v = (f32x4){0.f, 0.f, 0.f, 0.f};
        if (row < 6)                      v = *(const f32x4*)(vW2 + row * HID + col);
        else if (row >= 16 && row < 18)   v = *(const f32x4*)(pW2 + (row - 16) * HID + col);
        *(uint2*)(W2c + flat) = cvt4(v);
    }
}

// ---------------- main ------------------------------------------------------
__global__ __launch_bounds__(256, 3)
void intention_heads_kernel(const float* __restrict__ X,
                            const int* __restrict__ ids,
                            const __hip_bfloat16* __restrict__ Wc,
                            const __hip_bfloat16* __restrict__ W2c,
                            const float* __restrict__ vb1,
                            const float* __restrict__ pb1,
                            const float* __restrict__ vb2,
                            const float* __restrict__ pb2,
                            float* __restrict__ out)
{
    // LDS union: X staging A0/A1 (2 x 64x40 bf16 = 10.2KB) then H 64x264 bf16
    // (33.8KB). 33792 B -> 4 blocks/CU.
    __shared__ __align__(16) unsigned char smem[64 * HSTR * 2];
    __hip_bfloat16* A0 = (__hip_bfloat16*)smem;
    __hip_bfloat16* A1 = (__hip_bfloat16*)(smem + 64 * ASTR * 2);
    __hip_bfloat16* H  = (__hip_bfloat16*)smem;

    const int bx   = blockIdx.x;
    const int head = bx & 1;           // 0 = vehicle, 1 = pedestrian
    const int row0 = (bx >> 1) * 64;

    const int tid  = threadIdx.x;
    const int wave = tid >> 6;         // 0..3 -> hidden cols wave*64
    const int lane = tid & 63;
    const int quad = lane >> 4;
    const int l16  = lane & 15;
    const int wcol = wave * 64;

    // X staging: thread owns f32x4 at col q*4 of rows r2 and r2+32
    const int q  = tid & 7;
    const int r2 = tid >> 3;           // 0..31
    const float* Xs = X + (long)(row0 + r2) * DIM + q * 4;

    // B-frag row pointers (bf16 weights, row-major [n][k])
    const __hip_bfloat16* Wrow[4];
    #pragma unroll
    for (int j = 0; j < 4; ++j)
        Wrow[j] = Wc + (long)(head * 256 + wcol + j * 16 + l16) * DIM + quad * 8;

    f32x4 acc[4][4];
    #pragma unroll
    for (int i = 0; i < 4; ++i)
        #pragma unroll
        for (int j = 0; j < 4; ++j)
            acc[i][j] = (f32x4){0.f, 0.f, 0.f, 0.f};

    // prologue: stage X tile 0, load B frags 0
    {
        f32x4 pa0 = *(const f32x4*)(Xs);
        f32x4 pa1 = *(const f32x4*)(Xs + 32 * DIM);
        *(uint2*)&A0[r2 * ASTR + q * 4]        = cvt4(pa0);
        *(uint2*)&A0[(r2 + 32) * ASTR + q * 4] = cvt4(pa1);
    }
    short8 bcur[4];
    #pragma unroll
    for (int j = 0; j < 4; ++j)
        bcur[j] = *(const short8*)Wrow[j];
    __syncthreads();

    int p = 0;
    for (int it = 0; it < DIM / 32; ++it) {
        __hip_bfloat16* cur = p ? A1 : A0;
        __hip_bfloat16* nxt = p ? A0 : A1;

        short8 af[4];
        #pragma unroll
        for (int i = 0; i < 4; ++i)
            af[i] = *(const short8*)&cur[(i * 16 + l16) * ASTR + quad * 8];

        f32x4 na0, na1;
        short8 bnext[4];
        if (it < 15) {
            na0 = *(const f32x4*)(Xs + (it + 1) * 32);
            na1 = *(const f32x4*)(Xs + 32 * DIM + (it + 1) * 32);
            #pragma unroll
            for (int j = 0; j < 4; ++j)
                bnext[j] = *(const short8*)(Wrow[j] + (it + 1) * 32);
        }

        #pragma unroll
        for (int i = 0; i < 4; ++i)
            #pragma unroll
            for (int j = 0; j < 4; ++j)
                acc[i][j] = __builtin_amdgcn_mfma_f32_16x16x32_bf16(af[i], bcur[j], acc[i][j], 0, 0, 0);

        if (it < 15) {
            *(uint2*)&nxt[r2 * ASTR + q * 4]        = cvt4(na0);
            *(uint2*)&nxt[(r2 + 32) * ASTR + q * 4] = cvt4(na1);
            #pragma unroll
            for (int j = 0; j < 4; ++j)
                bcur[j] = bnext[j];
        }
        __syncthreads();
        p ^= 1;
    }

    // ------------- bias + GELU, stage H tile (bf16) -----------------------
    const float* b1 = head ? pb1 : vb1;
    float b1v[4];
    #pragma unroll
    for (int j = 0; j < 4; ++j)
        b1v[j] = b1[wcol + j * 16 + l16];

    #pragma unroll
    for (int i = 0; i < 4; ++i) {
        #pragma unroll
        for (int j = 0; j < 4; ++j) {
            const int col = wcol + j * 16 + l16;
            #pragma unroll
            for (int rr = 0; rr < 4; ++rr) {
                const int row = i * 16 + quad * 4 + rr;
                H[row * HSTR + col] = bf16rne(gelu_exact(acc[i][j][rr] + b1v[j]));
            }
        }
    }
    __syncthreads();

    // ------------- layer 2: H[64x256] @ W2^T (zero-padded to 16) ----------
    const float* b2 = head ? pb2 : vb2;
    const int nOut = head ? 2 : 6;

    f32x4 acc2 = (f32x4){0.f, 0.f, 0.f, 0.f};
    const int tokb = wave * 16;
    const short* hbase  = (const short*)&H[(tokb + l16) * HSTR + quad * 8];
    const __hip_bfloat16* w2base = W2c + (head * 16 + l16) * HID + quad * 8;
    #pragma unroll
    for (int k0 = 0; k0 < HID; k0 += 32) {
        short8 af    = *(const short8*)(hbase + k0);
        short8 bfrag = *(const short8*)(w2base + k0);   // zero rows pad n>=nOut
        acc2 = __builtin_amdgcn_mfma_f32_16x16x32_bf16(af, bfrag, acc2, 0, 0, 0);
    }

    // ------------- masked epilogue (f32 writes) ---------------------------
    const float b2v = (l16 < nOut) ? b2[l16] : 0.0f;

    #pragma unroll
    for (int rr = 0; rr < 4; ++rr) {
        const int t = row0 + tokb + quad * 4 + rr;
        const int type = ids[t];
        if (head == 0) {
            if (l16 == 0) {
                out[TOKENS * 6 + t] = (type == 1) ? 1.0f : 0.0f;
                out[TOKENS * 7 + t] = (type == 2) ? 1.0f : 0.0f;
            }
            if (l16 < 6) {
                if (type == 1)
                    out[t * 6 + l16] = acc2[rr] + b2v;
                else if (type != 2)
                    out[t * 6 + l16] = 0.0f;        // types 0,3 -> zeros
                // type==2 slots written by the pedestrian block
            }
        } else {
            if (l16 < 6 && type == 2)
                out[t * 6 + l16] = (l16 < 2) ? (acc2[rr] + b2v) : 0.0f;
        }
    }
}

extern "C" void kernel_launch(void* const* d_in, const int* in_sizes, int n_in,
                              void* d_out, int out_size, void* d_ws, size_t ws_size,
                              hipStream_t stream) {
    (void)n_in; (void)out_size; (void)ws_size;
    const float* X   = (const float*)d_in[0];
    const int*   ids = (const int*)d_in[1];
    const float* vW1 = (const float*)d_in[2];
    const float* vb1 = (const float*)d_in[3];
    const float* vW2 = (const float*)d_in[4];
    const float* vb2 = (const float*)d_in[5];
    const float* pW1 = (const float*)d_in[6];
    const float* pb1 = (const float*)d_in[7];
    const float* pW2 = (const float*)d_in[8];
    const float* pb2 = (const float*)d_in[9];
    float* out = (float*)d_out;

    // workspace: Wc [512*512] bf16 (512KB) ++ W2c [32*256] bf16 (16KB)
    __hip_bfloat16* Wc  = (__hip_bfloat16*)d_ws;
    __hip_bfloat16* W2c = Wc + 512 * DIM;

    hipLaunchKernelGGL(prep_kernel, dim3(264), dim3(256), 0, stream,
                       vW1, pW1, vW2, pW2, Wc, W2c);

    const int tokens = in_sizes[1];            // 65536
    const int grid   = (tokens / 64) * 2;      // token-tile x head

    hipLaunchKernelGGL(intention_heads_kernel, dim3(grid), dim3(256), 0, stream,
                       X, ids, Wc, W2c, vb1, pb1, vb2, pb2, out);
}